// Round 2
// baseline (142.404 us; speedup 1.0000x reference)
//
#include <hip/hip_runtime.h>
#include <hip/hip_bf16.h>

#define NRAYS 8192
#define SAMP  128
#define DVD   27
#define NFEAT 15

typedef float  f32x4  __attribute__((ext_vector_type(4)));
typedef short  short8 __attribute__((ext_vector_type(8)));
typedef unsigned int u32x2 __attribute__((ext_vector_type(2)));
typedef unsigned int u32x4 __attribute__((ext_vector_type(4)));

// ---- precomputed weight image in d_ws (shorts = bf16), FINAL LDS LAYOUT ----
//  W1t @0     [64][72]  B-frag rows = output col n, k = remapped enc dim
//  Ct  @4608  [64][72]  combined C = W2[:,1:16] @ V1[0:15,:]  (k = hidden dim)
//  W2s @9216  [16][72]  sigma column: row0 = W2[:,0], rows 1..15 zero
//  V2t @10368 [3][72]
//  gvc @byte 21168: float[64] = c1 + b2[1:16] @ V1[0:15,:]
#define IMG_W1   0
#define IMG_C    4608
#define IMG_W2S  9216
#define IMG_V2   10368
#define IMG_SHORTS 10584          // 21168 bytes
#define GVC_OFF  21168

// fast fp32 -> bf16 (round-half-up): store HIGH short of (bits + 0x8000)
static __device__ __forceinline__ void stbf(short* p, float x) {
    union { unsigned u; struct { short lo, hi; } s; } v;
    v.u = __float_as_uint(x) + 0x8000u;
    *p = v.s.hi;
}
static __device__ __forceinline__ float bf2f(short s) {
    return __uint_as_float(((unsigned)(unsigned short)s) << 16);
}
// pack two fp32 -> dword of two bf16 (lo -> low half), HW RNE convert
static __device__ __forceinline__ unsigned pk2bf(float lo, float hi) {
    unsigned r;
    asm("v_cvt_pk_bf16_f32 %0, %1, %2" : "=v"(r) : "v"(lo), "v"(hi));
    return r;
}
static __device__ __forceinline__ float sin_fast(float x) {
    float r = x * 0.15915494309189535f;
    r = r - floorf(r);
    return __builtin_amdgcn_sinf(r);
}
static __device__ __forceinline__ float cos_fast(float x) {
    float r = x * 0.15915494309189535f;
    r = r - floorf(r);
    return __builtin_amdgcn_cosf(r);
}

// E k-layout (shorts within a 72-short row):
//   bands 0..4 : k = 6*b + {sx,sy,sz,cx,cy,cz}   (dwords 0..14, written by half0)
//   px,py      : k = 30,31                        (dword 15, half0)
//   bands 5..9 : k = 32 + 6*(b-5) + {...}         (dwords 16..30, half1)
//   pz, 1.0    : k = 62,63                        (dword 31, half1; bias col = b1 row)
static __device__ __forceinline__ int kmap(int r) {
    if (r == 0) return 30;
    if (r == 1) return 31;
    if (r == 2) return 62;
    const int q = r - 3, i = q / 6, c = q - 6 * i;
    return (i < 5 ? 6 * i : 32 + 6 * (i - 5)) + c;
}

// ---------------- prep kernel: build weight image once ----------------
__global__ void __launch_bounds__(256)
prep_kernel(const float* __restrict__ W1, const float* __restrict__ b1,
            const float* __restrict__ W2, const float* __restrict__ b2,
            const float* __restrict__ V1, const float* __restrict__ c1,
            const float* __restrict__ V2, short* __restrict__ img,
            float* __restrict__ gvc) {
    const int g = blockIdx.x * 256 + threadIdx.x;   // 0..8191, 32 blocks
    // duty 1: W1 remap / b1 / combined C
    if (g < 4032) {                       // W1 [63][64] row-major
        const int r = g >> 6, n = g & 63;
        stbf(&img[IMG_W1 + n * 72 + kmap(r)], W1[g]);
    } else if (g < 4096) {                // bias column k=63 = b1
        const int n = g - 4032;
        stbf(&img[IMG_W1 + n * 72 + 63], b1[n]);
    } else {                              // C[k][n] = sum_j W2[k][1+j]*V1[j][n]
        const int i = g - 4096;
        const int k = i >> 6, n = i & 63;
        float a = 0.0f;
        #pragma unroll
        for (int j = 0; j < 15; j++) a += W2[k * 16 + 1 + j] * V1[j * 64 + n];
        stbf(&img[IMG_C + n * 72 + k], a);
    }
    // duty 2: sigma col / V2 / gvc / zero-fill of pads
    if (g < 64) {
        stbf(&img[IMG_W2S + g], W2[g * 16]);            // row n=0, k=g
    } else if (g < 256) {
        const int i = g - 64, k = i / 3, n = i - 3 * k; // V2 [64][3]
        stbf(&img[IMG_V2 + n * 72 + k], V2[i]);
    } else if (g < 320) {
        const int n = g - 256;
        float a = c1[n];
        #pragma unroll
        for (int j = 0; j < 15; j++) a += b2[1 + j] * V1[j * 64 + n];
        gvc[n] = a;
    } else if (g < 1496) {                // zero the k=64..71 pads of all 147 rows
        const int z = g - 320, row = z >> 3, c = z & 7;
        int base;
        if (row < 64)       base = IMG_W1  + row * 72;
        else if (row < 128) base = IMG_C   + (row - 64) * 72;
        else if (row < 144) base = IMG_W2S + (row - 128) * 72;
        else                base = IMG_V2  + (row - 144) * 72;
        img[base + 64 + c] = 0;
    } else if (g < 2456) {                // zero W2s rows 1..15, k=0..63
        const int z = g - 1496, n = 1 + (z >> 6), k = z & 63;
        img[IMG_W2S + n * 72 + k] = 0;
    }
}

// LDS layout:
//   staging (pre-b2): img copy @0 .. 21168
//   working (post-b2): sE@0 [4][32*72]s 18432B
//   persistent: sOm@21184 [4][128]f 2048, sRgb@23232 [4][384]s 3072,
//               sVde@26304 [4][28]f 448, sRed@26752 [4]f 16  -> 26768 B
#define SMEM_BYTES 26768

__global__ void __launch_bounds__(256)
march_kernel(const float* __restrict__ orig,
             const float* __restrict__ dirs,
             const float* __restrict__ tmin,
             const float* __restrict__ tmax,
             const float* __restrict__ b2,
             const float* __restrict__ c2,
             const float* __restrict__ V1,
             const short* __restrict__ img,
             const float* __restrict__ gvc,
             float* __restrict__ out) {
    __shared__ __align__(16) char smem[SMEM_BYTES];
    short* const sW1t = (short*)(smem);            // [64][72]
    short* const sCt  = (short*)(smem + 9216);     // [64][72]
    short* const sW2s = (short*)(smem + 18432);    // [16][72]
    short* const sV2t = (short*)(smem + 20736);    // [3][72]
    short* const sEa  = (short*)(smem);            // [wave][32*72]
    float* const sOm  = (float*)(smem + 21184);    // [wave][128]
    short* const sRgb = (short*)(smem + 23232);    // [wave][384]
    float* const sVde = (float*)(smem + 26304);    // [wave][28]
    float* const sRed = (float*)(smem + 26752);    // [4]

    const int tid  = threadIdx.x;
    const int lane = tid & 63;
    const int wave = tid >> 6;
    const int ray  = blockIdx.x * 4 + wave;

    // ---- block-redundant dt partial: sum(tmax - tmin) ----
    {
        const float4* tm0 = (const float4*)tmin;
        const float4* tm1 = (const float4*)tmax;
        float s = 0.0f;
        #pragma unroll
        for (int it = 0; it < 8; it++) {
            const int i = tid + it * 256;
            const float4 a = tm1[i], b = tm0[i];
            s += (a.x - b.x) + (a.y - b.y) + (a.z - b.z) + (a.w - b.w);
        }
        #pragma unroll
        for (int off = 32; off > 0; off >>= 1)
            s += __shfl_xor(s, off, 64);
        if (lane == 0) sRed[wave] = s;
    }

    // ---- weight staging: straight copy of the prebuilt image ----
    {
        const u32x4* src = (const u32x4*)img;
        u32x4* dst = (u32x4*)smem;
        #pragma unroll
        for (int it = 0; it < 6; it++) {
            const int i = tid + it * 256;
            if (i < IMG_SHORTS / 8) dst[i] = src[i];
        }
    }

    // ---- per-ray scalars ----
    const float ox = orig[ray * 3 + 0];
    const float oy = orig[ray * 3 + 1];
    const float oz = orig[ray * 3 + 2];
    const float dx = dirs[ray * 3 + 0];
    const float dy = dirs[ray * 3 + 1];
    const float dz = dirs[ray * 3 + 2];
    const float t0v = tmin[ray];
    const float trange = tmax[ray] - t0v;

    // ---- view-dir encoding (fp32) -> sVde (per-wave) ----
    {
        const float nrm = sqrtf(dx * dx + dy * dy + dz * dz);
        const float inv = 1.0f / (nrm + 1e-8f);
        const float vx = dx * inv, vy = dy * inv, vz = dz * inv;
        if (lane < DVD) {
            float val;
            if (lane < 3) {
                val = (lane == 0) ? vx : ((lane == 1) ? vy : vz);
            } else {
                const int q = lane - 3;
                const int b = q / 6;
                const int r = q - 6 * b;
                const bool isSin = (r < 3);
                const int d = isSin ? r : (r - 3);
                const float comp = (d == 0) ? vx : ((d == 1) ? vy : vz);
                const float a = (float)(1 << b) * comp;
                val = isSin ? sin_fast(a) : cos_fast(a);
            }
            sVde[wave * 28 + lane] = val;
        }
    }
    __syncthreads();   // barrier 1: staging copy + dt reduce complete

    const float dtv = (sRed[0] + sRed[1] + sRed[2] + sRed[3]) *
                      (1.0f / ((float)NRAYS * (float)SAMP));

    const int nfr  = lane & 15;   // n (or m) within a 16-tile
    const int quad = lane >> 4;

    // ---- B-fragments (n-permuted: tile nt at lane nfr = global col 4*nfr+nt) ----
    short8 w1f[4][2], combf[4][2], w2sf[2], v2f[2];
    #pragma unroll
    for (int nt = 0; nt < 4; nt++)
        #pragma unroll
        for (int kt = 0; kt < 2; kt++) {
            w1f[nt][kt]   = *(const short8*)&sW1t[(4 * nfr + nt) * 72 + quad * 8 + kt * 32];
            combf[nt][kt] = *(const short8*)&sCt [(4 * nfr + nt) * 72 + quad * 8 + kt * 32];
        }
    #pragma unroll
    for (int kt = 0; kt < 2; kt++)
        w2sf[kt] = *(const short8*)&sW2s[nfr * 72 + quad * 8 + kt * 32];
    #pragma unroll
    for (int kt = 0; kt < 2; kt++) {
        if (nfr < 3)
            v2f[kt] = *(const short8*)&sV2t[nfr * 72 + quad * 8 + kt * 32];
        else
            v2f[kt] = (short8){0, 0, 0, 0, 0, 0, 0, 0};
    }

    const float bb2 = b2[0];
    const float bc2 = (nfr < 3) ? c2[nfr] : 0.0f;

    // ---- gv[nt] = gvc[n] + sum_q vde[q] * V1[15+q][n],  n = 4*nfr+nt ----
    float gv[4];
    {
        const f32x4 g0 = *(const f32x4*)&gvc[4 * nfr];
        gv[0] = g0.x; gv[1] = g0.y; gv[2] = g0.z; gv[3] = g0.w;
    }
    #pragma unroll 9
    for (int q = 0; q < DVD; q++) {
        const float e = sVde[wave * 28 + q];
        const f32x4 vv = *(const f32x4*)&V1[(NFEAT + q) * 64 + 4 * nfr];
        gv[0] += e * vv.x; gv[1] += e * vv.y;
        gv[2] += e * vv.z; gv[3] += e * vv.w;
    }
    __syncthreads();   // barrier 2: fragment reads done before sE overwrite

    short* const myE = sEa + wave * (32 * 72);

    const int sl   = lane >> 1;   // local sample 0..31 (enc phase)
    const int half = lane & 1;
    // chain seed frequency: half0 starts at band 0 (f=1), half1 at band 5 (f=32)
    const float fmul = half ? 5.0929581789406507f      // 32 / (2*pi)
                            : 0.15915494309189535f;    //  1 / (2*pi)

    #pragma unroll 1
    for (int qq = 0; qq < 4; qq++) {
        // --- positional encodings: registers -> 4x ds_write_b128 ---
        {
            const int s = qq * 32 + sl;
            const float t = t0v + (float)s * (1.0f / 127.0f) * trange;
            const float px = ox + dx * t, py = oy + dy * t, pz = oz + dz * t;
            float rx = px * fmul; rx -= floorf(rx);
            float ry = py * fmul; ry -= floorf(ry);
            float rz = pz * fmul; rz -= floorf(rz);
            float sx = __builtin_amdgcn_sinf(rx), cx = __builtin_amdgcn_cosf(rx);
            float sy = __builtin_amdgcn_sinf(ry), cy = __builtin_amdgcn_cosf(ry);
            float sz = __builtin_amdgcn_sinf(rz), cz = __builtin_amdgcn_cosf(rz);
            unsigned e[16] __attribute__((aligned(16)));
            #pragma unroll
            for (int j = 0; j < 5; j++) {
                e[3 * j + 0] = pk2bf(sx, sy);
                e[3 * j + 1] = pk2bf(sz, cx);
                e[3 * j + 2] = pk2bf(cy, cz);
                if (j < 4) {   // double-angle: s'=2sc, c'=1-2s^2
                    const float tx = sx + sx, ty = sy + sy, tz = sz + sz;
                    const float nsx = tx * cx, nsy = ty * cy, nsz = tz * cz;
                    cx = __builtin_fmaf(-tx, sx, 1.0f);
                    cy = __builtin_fmaf(-ty, sy, 1.0f);
                    cz = __builtin_fmaf(-tz, sz, 1.0f);
                    sx = nsx; sy = nsy; sz = nsz;
                }
            }
            e[15] = half ? pk2bf(pz, 1.0f) : pk2bf(px, py);
            u32x4* dst = (u32x4*)((unsigned*)&myE[sl * 72] + 16 * half);
            dst[0] = *(const u32x4*)&e[0];
            dst[1] = *(const u32x4*)&e[4];
            dst[2] = *(const u32x4*)&e[8];
            dst[3] = *(const u32x4*)&e[12];
        }
        // --- layer 1: h = relu(E @ W1 + b1)   (b1 folded via k=63 col) ---
        f32x4 acc1[2][4];
        #pragma unroll
        for (int mt = 0; mt < 2; mt++)
            #pragma unroll
            for (int nt = 0; nt < 4; nt++)
                acc1[mt][nt] = (f32x4){0.0f, 0.0f, 0.0f, 0.0f};
        {
            short8 af[2][2];
            #pragma unroll
            for (int mt = 0; mt < 2; mt++)
                #pragma unroll
                for (int kt = 0; kt < 2; kt++)
                    af[mt][kt] = *(const short8*)&myE[(nfr + 16 * mt) * 72 + quad * 8 + kt * 32];
            #pragma unroll
            for (int mt = 0; mt < 2; mt++)
                #pragma unroll
                for (int nt = 0; nt < 4; nt++)
                    #pragma unroll
                    for (int kt = 0; kt < 2; kt++)
                        acc1[mt][nt] = __builtin_amdgcn_mfma_f32_16x16x32_bf16(
                            af[mt][kt], w1f[nt][kt], acc1[mt][nt], 0, 0, 0);
        }
        // packed h epilogue: lane's 4 cols are global n = 4*nfr..4*nfr+3
        #pragma unroll
        for (int mt = 0; mt < 2; mt++)
            #pragma unroll
            for (int r = 0; r < 4; r++) {
                const int m = 4 * quad + r + 16 * mt;
                u32x2 hp;
                hp.x = pk2bf(fmaxf(acc1[mt][0][r], 0.0f),
                             fmaxf(acc1[mt][1][r], 0.0f));
                hp.y = pk2bf(fmaxf(acc1[mt][2][r], 0.0f),
                             fmaxf(acc1[mt][3][r], 0.0f));
                *(u32x2*)&myE[m * 72 + 4 * nfr] = hp;
            }
        // --- sigma (h @ w2_sigma + b2[0]) and g_pre (h @ C) in one pass ---
        f32x4 acc2[2];
        f32x4 acc3[2][4];
        acc2[0] = (f32x4){0.0f, 0.0f, 0.0f, 0.0f};
        acc2[1] = (f32x4){0.0f, 0.0f, 0.0f, 0.0f};
        #pragma unroll
        for (int mt = 0; mt < 2; mt++)
            #pragma unroll
            for (int nt = 0; nt < 4; nt++)
                acc3[mt][nt] = (f32x4){0.0f, 0.0f, 0.0f, 0.0f};
        {
            short8 ah[2][2];
            #pragma unroll
            for (int mt = 0; mt < 2; mt++)
                #pragma unroll
                for (int kt = 0; kt < 2; kt++)
                    ah[mt][kt] = *(const short8*)&myE[(nfr + 16 * mt) * 72 + quad * 8 + kt * 32];
            #pragma unroll
            for (int mt = 0; mt < 2; mt++)
                #pragma unroll
                for (int kt = 0; kt < 2; kt++)
                    acc2[mt] = __builtin_amdgcn_mfma_f32_16x16x32_bf16(
                        ah[mt][kt], w2sf[kt], acc2[mt], 0, 0, 0);
            #pragma unroll
            for (int mt = 0; mt < 2; mt++)
                #pragma unroll
                for (int nt = 0; nt < 4; nt++)
                    #pragma unroll
                    for (int kt = 0; kt < 2; kt++)
                        acc3[mt][nt] = __builtin_amdgcn_mfma_f32_16x16x32_bf16(
                            ah[mt][kt], combf[nt][kt], acc3[mt][nt], 0, 0, 0);
        }
        if (nfr == 0) {
            #pragma unroll
            for (int mt = 0; mt < 2; mt++)
                #pragma unroll
                for (int r = 0; r < 4; r++) {
                    const int m = 4 * quad + r + 16 * mt;
                    const float sg = fmaxf(acc2[mt][r] + bb2, 0.0f);
                    sOm[wave * 128 + qq * 32 + m] = __expf(-sg * dtv);
                }
        }
        // --- g = relu(g_pre + gv)  (c1, b2f@V1f, vde@V1v all inside gv) ---
        #pragma unroll
        for (int mt = 0; mt < 2; mt++)
            #pragma unroll
            for (int r = 0; r < 4; r++) {
                const int m = 4 * quad + r + 16 * mt;
                u32x2 gp;
                gp.x = pk2bf(fmaxf(acc3[mt][0][r] + gv[0], 0.0f),
                             fmaxf(acc3[mt][1][r] + gv[1], 0.0f));
                gp.y = pk2bf(fmaxf(acc3[mt][2][r] + gv[2], 0.0f),
                             fmaxf(acc3[mt][3][r] + gv[3], 0.0f));
                *(u32x2*)&myE[m * 72 + 4 * nfr] = gp;
            }
        // --- V2: rgb = sigmoid(g @ V2 + c2) ---
        f32x4 acc4[2];
        acc4[0] = (f32x4){0.0f, 0.0f, 0.0f, 0.0f};
        acc4[1] = (f32x4){0.0f, 0.0f, 0.0f, 0.0f};
        {
            short8 agg[2][2];
            #pragma unroll
            for (int mt = 0; mt < 2; mt++)
                #pragma unroll
                for (int kt = 0; kt < 2; kt++)
                    agg[mt][kt] = *(const short8*)&myE[(nfr + 16 * mt) * 72 + quad * 8 + kt * 32];
            #pragma unroll
            for (int mt = 0; mt < 2; mt++)
                #pragma unroll
                for (int kt = 0; kt < 2; kt++)
                    acc4[mt] = __builtin_amdgcn_mfma_f32_16x16x32_bf16(
                        agg[mt][kt], v2f[kt], acc4[mt], 0, 0, 0);
        }
        if (nfr < 3) {
            #pragma unroll
            for (int mt = 0; mt < 2; mt++)
                #pragma unroll
                for (int r = 0; r < 4; r++) {
                    const int m = 4 * quad + r + 16 * mt;
                    const float val = acc4[mt][r] + bc2;
                    stbf(&sRgb[wave * 384 + (qq * 32 + m) * 3 + nfr],
                         1.0f / (1.0f + __expf(-val)));
                }
        }
    }

    // ---- exclusive multiplicative scan + weighted reduce (per wave) ----
    const float om0 = sOm[wave * 128 + 2 * lane];
    const float om1 = sOm[wave * 128 + 2 * lane + 1];
    const float al0 = 1.0f - om0;
    const float al1 = 1.0f - om1;

    float inc = om0 * om1;
    #pragma unroll
    for (int off = 1; off < 64; off <<= 1) {
        const float q = __shfl_up(inc, off, 64);
        if (lane >= off) inc *= q;
    }
    float Texc = __shfl_up(inc, 1, 64);
    if (lane == 0) Texc = 1.0f;

    const float T0 = Texc;
    const float T1 = Texc * om0;
    const float a0 = (T0 > 1e-4f) ? 1.0f : 0.0f;
    const float a1 = (T1 > 1e-4f) ? 1.0f : 0.0f;
    const float w0 = T0 * al0 * a0;
    const float w1 = T1 * al1 * a1;

    float cr = w0 * bf2f(sRgb[wave * 384 + (2 * lane) * 3 + 0]) +
               w1 * bf2f(sRgb[wave * 384 + (2 * lane + 1) * 3 + 0]);
    float cg = w0 * bf2f(sRgb[wave * 384 + (2 * lane) * 3 + 1]) +
               w1 * bf2f(sRgb[wave * 384 + (2 * lane + 1) * 3 + 1]);
    float cb = w0 * bf2f(sRgb[wave * 384 + (2 * lane) * 3 + 2]) +
               w1 * bf2f(sRgb[wave * 384 + (2 * lane + 1) * 3 + 2]);
    float tp = (a0 > 0.0f ? om0 : 1.0f) * (a1 > 0.0f ? om1 : 1.0f);

    #pragma unroll
    for (int off = 32; off > 0; off >>= 1) {
        cr += __shfl_xor(cr, off, 64);
        cg += __shfl_xor(cg, off, 64);
        cb += __shfl_xor(cb, off, 64);
        tp *= __shfl_xor(tp, off, 64);
    }

    if (lane == 0) {
        out[ray * 3 + 0] = cr;
        out[ray * 3 + 1] = cg;
        out[ray * 3 + 2] = cb;
        out[NRAYS * 3 + ray] = tp;
    }
}

extern "C" void kernel_launch(void* const* d_in, const int* in_sizes, int n_in,
                              void* d_out, int out_size, void* d_ws, size_t ws_size,
                              hipStream_t stream) {
    const float* orig = (const float*)d_in[0];
    const float* dirs = (const float*)d_in[1];
    const float* tmin = (const float*)d_in[2];
    const float* tmax = (const float*)d_in[3];
    const float* W1   = (const float*)d_in[4];
    const float* b1   = (const float*)d_in[5];
    const float* W2   = (const float*)d_in[6];
    const float* b2   = (const float*)d_in[7];
    const float* V1   = (const float*)d_in[8];
    const float* c1   = (const float*)d_in[9];
    const float* V2   = (const float*)d_in[10];
    const float* c2   = (const float*)d_in[11];

    short* img = (short*)d_ws;
    float* gvc = (float*)((char*)d_ws + GVC_OFF);

    prep_kernel<<<32, 256, 0, stream>>>(W1, b1, W2, b2, V1, c1, V2, img, gvc);
    march_kernel<<<NRAYS / 4, 256, 0, stream>>>(orig, dirs, tmin, tmax,
                                                b2, c2, V1, img, gvc,
                                                (float*)d_out);
}

// Round 3
// 139.361 us; speedup vs baseline: 1.0218x; 1.0218x over previous
//
#include <hip/hip_runtime.h>
#include <hip/hip_bf16.h>

#define NRAYS 8192
#define SAMP  128
#define DVD   27
#define NFEAT 15

typedef float  f32x4  __attribute__((ext_vector_type(4)));
typedef short  short8 __attribute__((ext_vector_type(8)));
typedef unsigned int u32x2 __attribute__((ext_vector_type(2)));
typedef unsigned int u32x4 __attribute__((ext_vector_type(4)));

// ---- precomputed weight image in d_ws (shorts = bf16), FINAL LDS LAYOUT ----
//  W1t @0     [64][72]  B-frag rows = output col n, k = remapped enc dim
//  Ct  @4608  [64][72]  combined C = W2[:,1:16] @ V1[0:15,:]  (k = hidden dim)
//  W2s @9216  [16][72]  sigma column: row0 = W2[:,0], rows 1..15 zero
//  V2t @10368 [16][72]  rows 0..2 = V2 cols, rows 3..15 zero
//  gvc @byte 23040: float[64] = c1 + b2[1:16] @ V1[0:15,:]
#define IMG_W1   0
#define IMG_C    4608
#define IMG_W2S  9216
#define IMG_V2   10368
#define IMG_SHORTS 11520          // 23040 bytes
#define GVC_OFF  23040

// fast fp32 -> bf16 (round-half-up): store HIGH short of (bits + 0x8000)
static __device__ __forceinline__ void stbf(short* p, float x) {
    union { unsigned u; struct { short lo, hi; } s; } v;
    v.u = __float_as_uint(x) + 0x8000u;
    *p = v.s.hi;
}
static __device__ __forceinline__ float bf2f(short s) {
    return __uint_as_float(((unsigned)(unsigned short)s) << 16);
}
// pack two fp32 -> dword of two bf16 (lo -> low half), HW RNE convert
static __device__ __forceinline__ unsigned pk2bf(float lo, float hi) {
    unsigned r;
    asm("v_cvt_pk_bf16_f32 %0, %1, %2" : "=v"(r) : "v"(lo), "v"(hi));
    return r;
}
static __device__ __forceinline__ float sin_fast(float x) {
    float r = x * 0.15915494309189535f;
    r = r - floorf(r);
    return __builtin_amdgcn_sinf(r);
}
static __device__ __forceinline__ float cos_fast(float x) {
    float r = x * 0.15915494309189535f;
    r = r - floorf(r);
    return __builtin_amdgcn_cosf(r);
}

// E k-layout (shorts within a 72-short row):
//   bands 0..4 : k = 6*b + {sx,sy,sz,cx,cy,cz}   (dwords 0..14, written by half0)
//   px,py      : k = 30,31                        (dword 15, half0)
//   bands 5..9 : k = 32 + 6*(b-5) + {...}         (dwords 16..30, half1)
//   pz, 1.0    : k = 62,63                        (dword 31, half1; bias col = b1 row)
static __device__ __forceinline__ int kmap(int r) {
    if (r == 0) return 30;
    if (r == 1) return 31;
    if (r == 2) return 62;
    const int q = r - 3, i = q / 6, c = q - 6 * i;
    return (i < 5 ? 6 * i : 32 + 6 * (i - 5)) + c;
}

// ---------------- prep kernel: build weight image once ----------------
__global__ void __launch_bounds__(256)
prep_kernel(const float* __restrict__ W1, const float* __restrict__ b1,
            const float* __restrict__ W2, const float* __restrict__ b2,
            const float* __restrict__ V1, const float* __restrict__ c1,
            const float* __restrict__ V2, short* __restrict__ img,
            float* __restrict__ gvc) {
    const int g = blockIdx.x * 256 + threadIdx.x;   // 0..8191, 32 blocks
    // duty 1: W1 remap / b1 / combined C
    if (g < 4032) {                       // W1 [63][64] row-major
        const int r = g >> 6, n = g & 63;
        stbf(&img[IMG_W1 + n * 72 + kmap(r)], W1[g]);
    } else if (g < 4096) {                // bias column k=63 = b1
        const int n = g - 4032;
        stbf(&img[IMG_W1 + n * 72 + 63], b1[n]);
    } else {                              // C[k][n] = sum_j W2[k][1+j]*V1[j][n]
        const int i = g - 4096;
        const int k = i >> 6, n = i & 63;
        float a = 0.0f;
        #pragma unroll
        for (int j = 0; j < 15; j++) a += W2[k * 16 + 1 + j] * V1[j * 64 + n];
        stbf(&img[IMG_C + n * 72 + k], a);
    }
    // duty 2: sigma col / V2 / gvc / zero-fills
    if (g < 64) {
        stbf(&img[IMG_W2S + g], W2[g * 16]);            // row n=0, k=g
    } else if (g < 256) {
        const int i = g - 64, k = i / 3, n = i - 3 * k; // V2 [64][3]
        stbf(&img[IMG_V2 + n * 72 + k], V2[i]);
    } else if (g < 320) {
        const int n = g - 256;
        float a = c1[n];
        #pragma unroll
        for (int j = 0; j < 15; j++) a += b2[1 + j] * V1[j * 64 + n];
        gvc[n] = a;
    } else if (g < 1600) {                // zero the k=64..71 pads of all 160 rows
        const int z = g - 320, row = z >> 3, c = z & 7;
        int base;
        if (row < 64)       base = IMG_W1  + row * 72;
        else if (row < 128) base = IMG_C   + (row - 64) * 72;
        else if (row < 144) base = IMG_W2S + (row - 128) * 72;
        else                base = IMG_V2  + (row - 144) * 72;
        img[base + 64 + c] = 0;
    } else if (g < 2560) {                // zero W2s rows 1..15, k=0..63
        const int z = g - 1600, n = 1 + (z >> 6), k = z & 63;
        img[IMG_W2S + n * 72 + k] = 0;
    } else if (g < 3392) {                // zero V2t rows 3..15, k=0..63
        const int z = g - 2560, n = 3 + (z >> 6), k = z & 63;
        img[IMG_V2 + n * 72 + k] = 0;
    }
}

// LDS layout:
//   staging (pre-b2): img copy @0 .. 23040   (sW2s@18432, sV2t@20736 persist)
//   working (post-b2): sE@0 [4][32*72]s 18432B  (overwrites W1t/Ct only)
//   persistent: sOm@23040 [4][128]f 2048, sRgb@25088 [4][384]s 3072,
//               sVde@28160 [4][28]f 448, sRed@28608 [4]f 16  -> 28624 B
#define SMEM_BYTES 28624

__global__ void __launch_bounds__(256, 4)
march_kernel(const float* __restrict__ orig,
             const float* __restrict__ dirs,
             const float* __restrict__ tmin,
             const float* __restrict__ tmax,
             const float* __restrict__ b2,
             const float* __restrict__ c2,
             const float* __restrict__ V1,
             const short* __restrict__ img,
             const float* __restrict__ gvc,
             float* __restrict__ out) {
    __shared__ __align__(16) char smem[SMEM_BYTES];
    short* const sW1t = (short*)(smem);            // [64][72]
    short* const sCt  = (short*)(smem + 9216);     // [64][72]
    short* const sW2s = (short*)(smem + 18432);    // [16][72] (persists)
    short* const sV2t = (short*)(smem + 20736);    // [16][72] (persists)
    short* const sEa  = (short*)(smem);            // [wave][32*72]
    float* const sOm  = (float*)(smem + 23040);    // [wave][128]
    short* const sRgb = (short*)(smem + 25088);    // [wave][384]
    float* const sVde = (float*)(smem + 28160);    // [wave][28]
    float* const sRed = (float*)(smem + 28608);    // [4]

    const int tid  = threadIdx.x;
    const int lane = tid & 63;
    const int wave = tid >> 6;
    const int ray  = blockIdx.x * 4 + wave;

    // ---- block-redundant dt partial: sum(tmax - tmin) ----
    {
        const float4* tm0 = (const float4*)tmin;
        const float4* tm1 = (const float4*)tmax;
        float s = 0.0f;
        #pragma unroll
        for (int it = 0; it < 8; it++) {
            const int i = tid + it * 256;
            const float4 a = tm1[i], b = tm0[i];
            s += (a.x - b.x) + (a.y - b.y) + (a.z - b.z) + (a.w - b.w);
        }
        #pragma unroll
        for (int off = 32; off > 0; off >>= 1)
            s += __shfl_xor(s, off, 64);
        if (lane == 0) sRed[wave] = s;
    }

    // ---- weight staging: straight copy of the prebuilt image ----
    {
        const u32x4* src = (const u32x4*)img;
        u32x4* dst = (u32x4*)smem;
        #pragma unroll
        for (int it = 0; it < 6; it++) {
            const int i = tid + it * 256;
            if (i < IMG_SHORTS / 8) dst[i] = src[i];
        }
    }

    // ---- per-ray scalars ----
    const float ox = orig[ray * 3 + 0];
    const float oy = orig[ray * 3 + 1];
    const float oz = orig[ray * 3 + 2];
    const float dx = dirs[ray * 3 + 0];
    const float dy = dirs[ray * 3 + 1];
    const float dz = dirs[ray * 3 + 2];
    const float t0v = tmin[ray];
    const float trange = tmax[ray] - t0v;

    // ---- view-dir encoding (fp32) -> sVde (per-wave) ----
    {
        const float nrm = sqrtf(dx * dx + dy * dy + dz * dz);
        const float inv = 1.0f / (nrm + 1e-8f);
        const float vx = dx * inv, vy = dy * inv, vz = dz * inv;
        if (lane < DVD) {
            float val;
            if (lane < 3) {
                val = (lane == 0) ? vx : ((lane == 1) ? vy : vz);
            } else {
                const int q = lane - 3;
                const int b = q / 6;
                const int r = q - 6 * b;
                const bool isSin = (r < 3);
                const int d = isSin ? r : (r - 3);
                const float comp = (d == 0) ? vx : ((d == 1) ? vy : vz);
                const float a = (float)(1 << b) * comp;
                val = isSin ? sin_fast(a) : cos_fast(a);
            }
            sVde[wave * 28 + lane] = val;
        }
    }
    __syncthreads();   // barrier 1: staging copy + dt reduce complete

    const float dtv = (sRed[0] + sRed[1] + sRed[2] + sRed[3]) *
                      (1.0f / ((float)NRAYS * (float)SAMP));

    const int nfr  = lane & 15;   // n (or m) within a 16-tile
    const int quad = lane >> 4;

    // ---- gv[nt] = gvc[n] + sum_q vde[q] * V1[15+q][n],  n = 4*nfr+nt ----
    // (done BEFORE fragment loads to avoid a preamble register spike)
    float gv[4];
    {
        const f32x4 g0 = *(const f32x4*)&gvc[4 * nfr];
        gv[0] = g0.x; gv[1] = g0.y; gv[2] = g0.z; gv[3] = g0.w;
    }
    #pragma unroll 9
    for (int q = 0; q < DVD; q++) {
        const float e = sVde[wave * 28 + q];
        const f32x4 vv = *(const f32x4*)&V1[(NFEAT + q) * 64 + 4 * nfr];
        gv[0] += e * vv.x; gv[1] += e * vv.y;
        gv[2] += e * vv.z; gv[3] += e * vv.w;
    }

    // ---- persistent B-fragments (n-permuted: tile nt = global col 4*nfr+nt) ----
    short8 w1f[4][2], combf[4][2];
    #pragma unroll
    for (int nt = 0; nt < 4; nt++)
        #pragma unroll
        for (int kt = 0; kt < 2; kt++) {
            w1f[nt][kt]   = *(const short8*)&sW1t[(4 * nfr + nt) * 72 + quad * 8 + kt * 32];
            combf[nt][kt] = *(const short8*)&sCt [(4 * nfr + nt) * 72 + quad * 8 + kt * 32];
        }

    const float bb2 = b2[0];
    const float bc2 = (nfr < 3) ? c2[nfr] : 0.0f;

    __syncthreads();   // barrier 2: fragment reads done before sE overwrite

    short* const myE = sEa + wave * (32 * 72);

    const int sl   = lane >> 1;   // local sample 0..31 (enc phase)
    const int half = lane & 1;
    // chain seed frequency: half0 starts at band 0 (f=1), half1 at band 5 (f=32)
    const float fmul = half ? 5.0929581789406507f      // 32 / (2*pi)
                            : 0.15915494309189535f;    //  1 / (2*pi)

    #pragma unroll 1
    for (int qq = 0; qq < 4; qq++) {
        // --- positional encodings: registers -> 4x ds_write_b128 ---
        {
            const int s = qq * 32 + sl;
            const float t = t0v + (float)s * (1.0f / 127.0f) * trange;
            const float px = ox + dx * t, py = oy + dy * t, pz = oz + dz * t;
            float rx = px * fmul; rx -= floorf(rx);
            float ry = py * fmul; ry -= floorf(ry);
            float rz = pz * fmul; rz -= floorf(rz);
            float sx = __builtin_amdgcn_sinf(rx), cx = __builtin_amdgcn_cosf(rx);
            float sy = __builtin_amdgcn_sinf(ry), cy = __builtin_amdgcn_cosf(ry);
            float sz = __builtin_amdgcn_sinf(rz), cz = __builtin_amdgcn_cosf(rz);
            unsigned e[16] __attribute__((aligned(16)));
            #pragma unroll
            for (int j = 0; j < 5; j++) {
                e[3 * j + 0] = pk2bf(sx, sy);
                e[3 * j + 1] = pk2bf(sz, cx);
                e[3 * j + 2] = pk2bf(cy, cz);
                if (j < 4) {   // double-angle: s'=2sc, c'=1-2s^2
                    const float tx = sx + sx, ty = sy + sy, tz = sz + sz;
                    const float nsx = tx * cx, nsy = ty * cy, nsz = tz * cz;
                    cx = __builtin_fmaf(-tx, sx, 1.0f);
                    cy = __builtin_fmaf(-ty, sy, 1.0f);
                    cz = __builtin_fmaf(-tz, sz, 1.0f);
                    sx = nsx; sy = nsy; sz = nsz;
                }
            }
            e[15] = half ? pk2bf(pz, 1.0f) : pk2bf(px, py);
            u32x4* dst = (u32x4*)((unsigned*)&myE[sl * 72] + 16 * half);
            dst[0] = *(const u32x4*)&e[0];
            dst[1] = *(const u32x4*)&e[4];
            dst[2] = *(const u32x4*)&e[8];
            dst[3] = *(const u32x4*)&e[12];
        }
        // --- layer 1: h = relu(E @ W1 + b1)   (b1 folded via k=63 col) ---
        f32x4 acc1[2][4];
        #pragma unroll
        for (int mt = 0; mt < 2; mt++)
            #pragma unroll
            for (int nt = 0; nt < 4; nt++)
                acc1[mt][nt] = (f32x4){0.0f, 0.0f, 0.0f, 0.0f};
        {
            short8 af[2][2];
            #pragma unroll
            for (int mt = 0; mt < 2; mt++)
                #pragma unroll
                for (int kt = 0; kt < 2; kt++)
                    af[mt][kt] = *(const short8*)&myE[(nfr + 16 * mt) * 72 + quad * 8 + kt * 32];
            #pragma unroll
            for (int mt = 0; mt < 2; mt++)
                #pragma unroll
                for (int nt = 0; nt < 4; nt++)
                    #pragma unroll
                    for (int kt = 0; kt < 2; kt++)
                        acc1[mt][nt] = __builtin_amdgcn_mfma_f32_16x16x32_bf16(
                            af[mt][kt], w1f[nt][kt], acc1[mt][nt], 0, 0, 0);
        }
        // packed h epilogue: lane's 4 cols are global n = 4*nfr..4*nfr+3
        #pragma unroll
        for (int mt = 0; mt < 2; mt++)
            #pragma unroll
            for (int r = 0; r < 4; r++) {
                const int m = 4 * quad + r + 16 * mt;
                u32x2 hp;
                hp.x = pk2bf(fmaxf(acc1[mt][0][r], 0.0f),
                             fmaxf(acc1[mt][1][r], 0.0f));
                hp.y = pk2bf(fmaxf(acc1[mt][2][r], 0.0f),
                             fmaxf(acc1[mt][3][r], 0.0f));
                *(u32x2*)&myE[m * 72 + 4 * nfr] = hp;
            }
        // --- A-fragments of h (shared by sigma and C GEMMs) ---
        short8 ah[2][2];
        #pragma unroll
        for (int mt = 0; mt < 2; mt++)
            #pragma unroll
            for (int kt = 0; kt < 2; kt++)
                ah[mt][kt] = *(const short8*)&myE[(nfr + 16 * mt) * 72 + quad * 8 + kt * 32];
        // --- sigma: acc2 = b2[0] + h @ w2s   (init-by-value, consumed first) ---
        {
            f32x4 acc2[2];
            acc2[0] = (f32x4){bb2, bb2, bb2, bb2};
            acc2[1] = (f32x4){bb2, bb2, bb2, bb2};
            short8 w2sf[2];
            #pragma unroll
            for (int kt = 0; kt < 2; kt++)
                w2sf[kt] = *(const short8*)&sW2s[nfr * 72 + quad * 8 + kt * 32];
            #pragma unroll
            for (int mt = 0; mt < 2; mt++)
                #pragma unroll
                for (int kt = 0; kt < 2; kt++)
                    acc2[mt] = __builtin_amdgcn_mfma_f32_16x16x32_bf16(
                        ah[mt][kt], w2sf[kt], acc2[mt], 0, 0, 0);
            if (nfr == 0) {
                #pragma unroll
                for (int mt = 0; mt < 2; mt++)
                    #pragma unroll
                    for (int r = 0; r < 4; r++) {
                        const int m = 4 * quad + r + 16 * mt;
                        const float sg = fmaxf(acc2[mt][r], 0.0f);
                        sOm[wave * 128 + qq * 32 + m] = __expf(-sg * dtv);
                    }
            }
        }
        // --- g = relu(h @ C + gv)  (gv folded into acc init; reuses acc1 AGPRs) ---
        {
            f32x4 acc3[2][4];
            #pragma unroll
            for (int mt = 0; mt < 2; mt++)
                #pragma unroll
                for (int nt = 0; nt < 4; nt++)
                    acc3[mt][nt] = (f32x4){gv[nt], gv[nt], gv[nt], gv[nt]};
            #pragma unroll
            for (int mt = 0; mt < 2; mt++)
                #pragma unroll
                for (int nt = 0; nt < 4; nt++)
                    #pragma unroll
                    for (int kt = 0; kt < 2; kt++)
                        acc3[mt][nt] = __builtin_amdgcn_mfma_f32_16x16x32_bf16(
                            ah[mt][kt], combf[nt][kt], acc3[mt][nt], 0, 0, 0);
            #pragma unroll
            for (int mt = 0; mt < 2; mt++)
                #pragma unroll
                for (int r = 0; r < 4; r++) {
                    const int m = 4 * quad + r + 16 * mt;
                    u32x2 gp;
                    gp.x = pk2bf(fmaxf(acc3[mt][0][r], 0.0f),
                                 fmaxf(acc3[mt][1][r], 0.0f));
                    gp.y = pk2bf(fmaxf(acc3[mt][2][r], 0.0f),
                                 fmaxf(acc3[mt][3][r], 0.0f));
                    *(u32x2*)&myE[m * 72 + 4 * nfr] = gp;
                }
        }
        // --- V2: rgb = sigmoid(g @ V2 + c2)  (c2 folded into acc init) ---
        {
            f32x4 acc4[2];
            acc4[0] = (f32x4){bc2, bc2, bc2, bc2};
            acc4[1] = (f32x4){bc2, bc2, bc2, bc2};
            short8 agg[2][2];
            #pragma unroll
            for (int mt = 0; mt < 2; mt++)
                #pragma unroll
                for (int kt = 0; kt < 2; kt++)
                    agg[mt][kt] = *(const short8*)&myE[(nfr + 16 * mt) * 72 + quad * 8 + kt * 32];
            short8 v2f[2];
            #pragma unroll
            for (int kt = 0; kt < 2; kt++)
                v2f[kt] = *(const short8*)&sV2t[nfr * 72 + quad * 8 + kt * 32];
            #pragma unroll
            for (int mt = 0; mt < 2; mt++)
                #pragma unroll
                for (int kt = 0; kt < 2; kt++)
                    acc4[mt] = __builtin_amdgcn_mfma_f32_16x16x32_bf16(
                        agg[mt][kt], v2f[kt], acc4[mt], 0, 0, 0);
            if (nfr < 3) {
                #pragma unroll
                for (int mt = 0; mt < 2; mt++)
                    #pragma unroll
                    for (int r = 0; r < 4; r++) {
                        const int m = 4 * quad + r + 16 * mt;
                        const float val = acc4[mt][r];
                        stbf(&sRgb[wave * 384 + (qq * 32 + m) * 3 + nfr],
                             1.0f / (1.0f + __expf(-val)));
                    }
            }
        }
    }

    // ---- exclusive multiplicative scan + weighted reduce (per wave) ----
    const float om0 = sOm[wave * 128 + 2 * lane];
    const float om1 = sOm[wave * 128 + 2 * lane + 1];
    const float al0 = 1.0f - om0;
    const float al1 = 1.0f - om1;

    float inc = om0 * om1;
    #pragma unroll
    for (int off = 1; off < 64; off <<= 1) {
        const float q = __shfl_up(inc, off, 64);
        if (lane >= off) inc *= q;
    }
    float Texc = __shfl_up(inc, 1, 64);
    if (lane == 0) Texc = 1.0f;

    const float T0 = Texc;
    const float T1 = Texc * om0;
    const float a0 = (T0 > 1e-4f) ? 1.0f : 0.0f;
    const float a1 = (T1 > 1e-4f) ? 1.0f : 0.0f;
    const float w0 = T0 * al0 * a0;
    const float w1 = T1 * al1 * a1;

    float cr = w0 * bf2f(sRgb[wave * 384 + (2 * lane) * 3 + 0]) +
               w1 * bf2f(sRgb[wave * 384 + (2 * lane + 1) * 3 + 0]);
    float cg = w0 * bf2f(sRgb[wave * 384 + (2 * lane) * 3 + 1]) +
               w1 * bf2f(sRgb[wave * 384 + (2 * lane + 1) * 3 + 1]);
    float cb = w0 * bf2f(sRgb[wave * 384 + (2 * lane) * 3 + 2]) +
               w1 * bf2f(sRgb[wave * 384 + (2 * lane + 1) * 3 + 2]);
    float tp = (a0 > 0.0f ? om0 : 1.0f) * (a1 > 0.0f ? om1 : 1.0f);

    #pragma unroll
    for (int off = 32; off > 0; off >>= 1) {
        cr += __shfl_xor(cr, off, 64);
        cg += __shfl_xor(cg, off, 64);
        cb += __shfl_xor(cb, off, 64);
        tp *= __shfl_xor(tp, off, 64);
    }

    if (lane == 0) {
        out[ray * 3 + 0] = cr;
        out[ray * 3 + 1] = cg;
        out[ray * 3 + 2] = cb;
        out[NRAYS * 3 + ray] = tp;
    }
}

extern "C" void kernel_launch(void* const* d_in, const int* in_sizes, int n_in,
                              void* d_out, int out_size, void* d_ws, size_t ws_size,
                              hipStream_t stream) {
    const float* orig = (const float*)d_in[0];
    const float* dirs = (const float*)d_in[1];
    const float* tmin = (const float*)d_in[2];
    const float* tmax = (const float*)d_in[3];
    const float* W1   = (const float*)d_in[4];
    const float* b1   = (const float*)d_in[5];
    const float* W2   = (const float*)d_in[6];
    const float* b2   = (const float*)d_in[7];
    const float* V1   = (const float*)d_in[8];
    const float* c1   = (const float*)d_in[9];
    const float* V2   = (const float*)d_in[10];
    const float* c2   = (const float*)d_in[11];

    short* img = (short*)d_ws;
    float* gvc = (float*)((char*)d_ws + GVC_OFF);

    prep_kernel<<<32, 256, 0, stream>>>(W1, b1, W2, b2, V1, c1, V2, img, gvc);
    march_kernel<<<NRAYS / 4, 256, 0, stream>>>(orig, dirs, tmin, tmax,
                                                b2, c2, V1, img, gvc,
                                                (float*)d_out);
}

// Round 4
// 120.357 us; speedup vs baseline: 1.1832x; 1.1579x over previous
//
#include <hip/hip_runtime.h>
#include <hip/hip_bf16.h>

#define NRAYS 8192
#define SAMP  128
#define DVD   27
#define NFEAT 15

typedef float  f32x4  __attribute__((ext_vector_type(4)));
typedef short  short8 __attribute__((ext_vector_type(8)));
typedef unsigned int u32x2 __attribute__((ext_vector_type(2)));
typedef unsigned int u32x4 __attribute__((ext_vector_type(4)));

// ---- precomputed weight image in d_ws (shorts = bf16) ----
//  W1t @0     [64][72]  B-frag rows = output col n, k = remapped enc dim
//  Ct  @4608  [64][72]  combined C = W2[:,1:16] @ V1[0:15,:]  (k = hidden dim)
//  W2s @9216  [16][72]  sigma column: row0 = W2[:,0], rows 1..15 zero
//  V2t @10368 [16][72]  rows 0..2 = V2 cols, rows 3..15 zero
//  gvc @byte 23040: float[64] = c1 + b2[1:16] @ V1[0:15,:]
#define IMG_W1   0
#define IMG_C    4608
#define IMG_W2S  9216
#define IMG_V2   10368
#define IMG_SHORTS 11520          // 23040 bytes
#define GVC_OFF  23040

// fast fp32 -> bf16 (round-half-up): store HIGH short of (bits + 0x8000)
static __device__ __forceinline__ void stbf(short* p, float x) {
    union { unsigned u; struct { short lo, hi; } s; } v;
    v.u = __float_as_uint(x) + 0x8000u;
    *p = v.s.hi;
}
static __device__ __forceinline__ float bf2f(short s) {
    return __uint_as_float(((unsigned)(unsigned short)s) << 16);
}
// pack two fp32 -> dword of two bf16 (lo -> low half), HW RNE convert
static __device__ __forceinline__ unsigned pk2bf(float lo, float hi) {
    unsigned r;
    asm("v_cvt_pk_bf16_f32 %0, %1, %2" : "=v"(r) : "v"(lo), "v"(hi));
    return r;
}
static __device__ __forceinline__ float sin_fast(float x) {
    float r = x * 0.15915494309189535f;
    r = r - floorf(r);
    return __builtin_amdgcn_sinf(r);
}
static __device__ __forceinline__ float cos_fast(float x) {
    float r = x * 0.15915494309189535f;
    r = r - floorf(r);
    return __builtin_amdgcn_cosf(r);
}

// E k-layout (shorts within a 72-short row):
//   bands 0..4 : k = 6*b + {sx,sy,sz,cx,cy,cz}   (dwords 0..14, written by half0)
//   px,py      : k = 30,31                        (dword 15, half0)
//   bands 5..9 : k = 32 + 6*(b-5) + {...}         (dwords 16..30, half1)
//   pz, 1.0    : k = 62,63                        (dword 31, half1; bias col = b1 row)
static __device__ __forceinline__ int kmap(int r) {
    if (r == 0) return 30;
    if (r == 1) return 31;
    if (r == 2) return 62;
    const int q = r - 3, i = q / 6, c = q - 6 * i;
    return (i < 5 ? 6 * i : 32 + 6 * (i - 5)) + c;
}

// ---------------- prep kernel: build weight image once ----------------
__global__ void __launch_bounds__(256)
prep_kernel(const float* __restrict__ W1, const float* __restrict__ b1,
            const float* __restrict__ W2, const float* __restrict__ b2,
            const float* __restrict__ V1, const float* __restrict__ c1,
            const float* __restrict__ V2, short* __restrict__ img,
            float* __restrict__ gvc) {
    const int g = blockIdx.x * 256 + threadIdx.x;   // 0..8191, 32 blocks
    // duty 1: W1 remap / b1 / combined C
    if (g < 4032) {                       // W1 [63][64] row-major
        const int r = g >> 6, n = g & 63;
        stbf(&img[IMG_W1 + n * 72 + kmap(r)], W1[g]);
    } else if (g < 4096) {                // bias column k=63 = b1
        const int n = g - 4032;
        stbf(&img[IMG_W1 + n * 72 + 63], b1[n]);
    } else {                              // C[k][n] = sum_j W2[k][1+j]*V1[j][n]
        const int i = g - 4096;
        const int k = i >> 6, n = i & 63;
        float a = 0.0f;
        #pragma unroll
        for (int j = 0; j < 15; j++) a += W2[k * 16 + 1 + j] * V1[j * 64 + n];
        stbf(&img[IMG_C + n * 72 + k], a);
    }
    // duty 2: sigma col / V2 / gvc / zero-fills
    if (g < 64) {
        stbf(&img[IMG_W2S + g], W2[g * 16]);            // row n=0, k=g
    } else if (g < 256) {
        const int i = g - 64, k = i / 3, n = i - 3 * k; // V2 [64][3]
        stbf(&img[IMG_V2 + n * 72 + k], V2[i]);
    } else if (g < 320) {
        const int n = g - 256;
        float a = c1[n];
        #pragma unroll
        for (int j = 0; j < 15; j++) a += b2[1 + j] * V1[j * 64 + n];
        gvc[n] = a;
    } else if (g < 1600) {                // zero the k=64..71 pads of all 160 rows
        const int z = g - 320, row = z >> 3, c = z & 7;
        int base;
        if (row < 64)       base = IMG_W1  + row * 72;
        else if (row < 128) base = IMG_C   + (row - 64) * 72;
        else if (row < 144) base = IMG_W2S + (row - 128) * 72;
        else                base = IMG_V2  + (row - 144) * 72;
        img[base + 64 + c] = 0;
    } else if (g < 2560) {                // zero W2s rows 1..15, k=0..63
        const int z = g - 1600, n = 1 + (z >> 6), k = z & 63;
        img[IMG_W2S + n * 72 + k] = 0;
    } else if (g < 3392) {                // zero V2t rows 3..15, k=0..63
        const int z = g - 2560, n = 3 + (z >> 6), k = z & 63;
        img[IMG_V2 + n * 72 + k] = 0;
    }
}

// LDS layout:
//   overlay region [0,18432): staged W1t [64][72] (dead after frag load),
//                             then sE [4][32*72]
//   persistent: sCt@18432 [64][72] 9216, sW2s@27648 [16][72] 2304,
//               sV2t@29952 [16][72] 2304, sOm@32256 [4][128]f 2048,
//               sRgb@34304 [4][384]s 3072, sVde@37376 [4][28]f 448,
//               sRed@37824 [4]f 16  -> 37840 B  (4 blocks/CU)
#define SMEM_BYTES 37840

__global__ void __launch_bounds__(256, 4)
march_kernel(const float* __restrict__ orig,
             const float* __restrict__ dirs,
             const float* __restrict__ tmin,
             const float* __restrict__ tmax,
             const float* __restrict__ b2,
             const float* __restrict__ c2,
             const float* __restrict__ V1,
             const short* __restrict__ img,
             const float* __restrict__ gvc,
             float* __restrict__ out) {
    __shared__ __align__(16) char smem[SMEM_BYTES];
    short* const sW1t = (short*)(smem);            // [64][72] staging (overlaid)
    short* const sEa  = (short*)(smem);            // [wave][32*72]
    short* const sCt  = (short*)(smem + 18432);    // [64][72] persistent
    short* const sW2s = (short*)(smem + 27648);    // [16][72] persistent
    short* const sV2t = (short*)(smem + 29952);    // [16][72] persistent
    float* const sOm  = (float*)(smem + 32256);    // [wave][128]
    short* const sRgb = (short*)(smem + 34304);    // [wave][384]
    float* const sVde = (float*)(smem + 37376);    // [wave][28]
    float* const sRed = (float*)(smem + 37824);    // [4]

    const int tid  = threadIdx.x;
    const int lane = tid & 63;
    const int wave = tid >> 6;
    const int ray  = blockIdx.x * 4 + wave;

    // ---- block-redundant dt partial: sum(tmax - tmin) ----
    {
        const float4* tm0 = (const float4*)tmin;
        const float4* tm1 = (const float4*)tmax;
        float s = 0.0f;
        #pragma unroll
        for (int it = 0; it < 8; it++) {
            const int i = tid + it * 256;
            const float4 a = tm1[i], b = tm0[i];
            s += (a.x - b.x) + (a.y - b.y) + (a.z - b.z) + (a.w - b.w);
        }
        #pragma unroll
        for (int off = 32; off > 0; off >>= 1)
            s += __shfl_xor(s, off, 64);
        if (lane == 0) sRed[wave] = s;
    }

    // ---- weight staging: copy prebuilt image (W1t -> @0, rest -> @18432) ----
    {
        const u32x4* src = (const u32x4*)img;
        u32x4* dst = (u32x4*)smem;
        #pragma unroll
        for (int it = 0; it < 6; it++) {
            const int i = tid + it * 256;
            if (i < 1440) {                 // 23040 B / 16
                const int d = (i < 576) ? i : i + 576;   // skip sE upper half
                dst[d] = src[i];
            }
        }
    }

    // ---- per-ray scalars ----
    const float ox = orig[ray * 3 + 0];
    const float oy = orig[ray * 3 + 1];
    const float oz = orig[ray * 3 + 2];
    const float dx = dirs[ray * 3 + 0];
    const float dy = dirs[ray * 3 + 1];
    const float dz = dirs[ray * 3 + 2];
    const float t0v = tmin[ray];
    const float trange = tmax[ray] - t0v;

    // ---- view-dir encoding (fp32) -> sVde (per-wave) ----
    {
        const float nrm = sqrtf(dx * dx + dy * dy + dz * dz);
        const float inv = 1.0f / (nrm + 1e-8f);
        const float vx = dx * inv, vy = dy * inv, vz = dz * inv;
        if (lane < DVD) {
            float val;
            if (lane < 3) {
                val = (lane == 0) ? vx : ((lane == 1) ? vy : vz);
            } else {
                const int q = lane - 3;
                const int b = q / 6;
                const int r = q - 6 * b;
                const bool isSin = (r < 3);
                const int d = isSin ? r : (r - 3);
                const float comp = (d == 0) ? vx : ((d == 1) ? vy : vz);
                const float a = (float)(1 << b) * comp;
                val = isSin ? sin_fast(a) : cos_fast(a);
            }
            sVde[wave * 28 + lane] = val;
        }
    }
    __syncthreads();   // barrier 1: staging copy + dt reduce complete

    const float dtv = (sRed[0] + sRed[1] + sRed[2] + sRed[3]) *
                      (1.0f / ((float)NRAYS * (float)SAMP));

    const int nfr  = lane & 15;   // n (or m) within a 16-tile
    const int quad = lane >> 4;

    // ---- gv[nt] = gvc[n] + sum_q vde[q] * V1[15+q][n],  n = 4*nfr+nt ----
    float gv[4];
    {
        const f32x4 g0 = *(const f32x4*)&gvc[4 * nfr];
        gv[0] = g0.x; gv[1] = g0.y; gv[2] = g0.z; gv[3] = g0.w;
    }
    #pragma unroll 9
    for (int q = 0; q < DVD; q++) {
        const float e = sVde[wave * 28 + q];
        const f32x4 vv = *(const f32x4*)&V1[(NFEAT + q) * 64 + 4 * nfr];
        gv[0] += e * vv.x; gv[1] += e * vv.y;
        gv[2] += e * vv.z; gv[3] += e * vv.w;
    }

    // ---- persistent W1 B-fragments (n-permuted: tile nt = global col 4*nfr+nt)
    // (Ct stays in LDS and is re-read per qq — keeps unified regs under 128)
    short8 w1f[4][2];
    #pragma unroll
    for (int nt = 0; nt < 4; nt++)
        #pragma unroll
        for (int kt = 0; kt < 2; kt++)
            w1f[nt][kt] = *(const short8*)&sW1t[(4 * nfr + nt) * 72 + quad * 8 + kt * 32];

    const float bb2 = b2[0];
    const float bc2 = (nfr < 3) ? c2[nfr] : 0.0f;

    __syncthreads();   // barrier 2: W1t fragment reads done before sE overwrite

    short* const myE = sEa + wave * (32 * 72);

    const int sl   = lane >> 1;   // local sample 0..31 (enc phase)
    const int half = lane & 1;
    // chain seed frequency: half0 starts at band 0 (f=1), half1 at band 5 (f=32)
    const float fmul = half ? 5.0929581789406507f      // 32 / (2*pi)
                            : 0.15915494309189535f;    //  1 / (2*pi)

    #pragma unroll 1
    for (int qq = 0; qq < 4; qq++) {
        // --- positional encodings: registers -> 4x ds_write_b128 ---
        {
            const int s = qq * 32 + sl;
            const float t = t0v + (float)s * (1.0f / 127.0f) * trange;
            const float px = ox + dx * t, py = oy + dy * t, pz = oz + dz * t;
            float rx = px * fmul; rx -= floorf(rx);
            float ry = py * fmul; ry -= floorf(ry);
            float rz = pz * fmul; rz -= floorf(rz);
            float sx = __builtin_amdgcn_sinf(rx), cx = __builtin_amdgcn_cosf(rx);
            float sy = __builtin_amdgcn_sinf(ry), cy = __builtin_amdgcn_cosf(ry);
            float sz = __builtin_amdgcn_sinf(rz), cz = __builtin_amdgcn_cosf(rz);
            unsigned e[16] __attribute__((aligned(16)));
            #pragma unroll
            for (int j = 0; j < 5; j++) {
                e[3 * j + 0] = pk2bf(sx, sy);
                e[3 * j + 1] = pk2bf(sz, cx);
                e[3 * j + 2] = pk2bf(cy, cz);
                if (j < 4) {   // double-angle: s'=2sc, c'=1-2s^2
                    const float tx = sx + sx, ty = sy + sy, tz = sz + sz;
                    const float nsx = tx * cx, nsy = ty * cy, nsz = tz * cz;
                    cx = __builtin_fmaf(-tx, sx, 1.0f);
                    cy = __builtin_fmaf(-ty, sy, 1.0f);
                    cz = __builtin_fmaf(-tz, sz, 1.0f);
                    sx = nsx; sy = nsy; sz = nsz;
                }
            }
            e[15] = half ? pk2bf(pz, 1.0f) : pk2bf(px, py);
            u32x4* dst = (u32x4*)((unsigned*)&myE[sl * 72] + 16 * half);
            dst[0] = *(const u32x4*)&e[0];
            dst[1] = *(const u32x4*)&e[4];
            dst[2] = *(const u32x4*)&e[8];
            dst[3] = *(const u32x4*)&e[12];
        }
        // --- layer 1: h = relu(E @ W1 + b1)   (b1 folded via k=63 col) ---
        f32x4 acc1[2][4];
        #pragma unroll
        for (int mt = 0; mt < 2; mt++)
            #pragma unroll
            for (int nt = 0; nt < 4; nt++)
                acc1[mt][nt] = (f32x4){0.0f, 0.0f, 0.0f, 0.0f};
        {
            short8 af[2][2];
            #pragma unroll
            for (int mt = 0; mt < 2; mt++)
                #pragma unroll
                for (int kt = 0; kt < 2; kt++)
                    af[mt][kt] = *(const short8*)&myE[(nfr + 16 * mt) * 72 + quad * 8 + kt * 32];
            #pragma unroll
            for (int mt = 0; mt < 2; mt++)
                #pragma unroll
                for (int nt = 0; nt < 4; nt++)
                    #pragma unroll
                    for (int kt = 0; kt < 2; kt++)
                        acc1[mt][nt] = __builtin_amdgcn_mfma_f32_16x16x32_bf16(
                            af[mt][kt], w1f[nt][kt], acc1[mt][nt], 0, 0, 0);
        }
        // packed h epilogue: lane's 4 cols are global n = 4*nfr..4*nfr+3
        #pragma unroll
        for (int mt = 0; mt < 2; mt++)
            #pragma unroll
            for (int r = 0; r < 4; r++) {
                const int m = 4 * quad + r + 16 * mt;
                u32x2 hp;
                hp.x = pk2bf(fmaxf(acc1[mt][0][r], 0.0f),
                             fmaxf(acc1[mt][1][r], 0.0f));
                hp.y = pk2bf(fmaxf(acc1[mt][2][r], 0.0f),
                             fmaxf(acc1[mt][3][r], 0.0f));
                *(u32x2*)&myE[m * 72 + 4 * nfr] = hp;
            }
        // --- A-fragments of h (shared by sigma and C GEMMs) ---
        short8 ah[2][2];
        #pragma unroll
        for (int mt = 0; mt < 2; mt++)
            #pragma unroll
            for (int kt = 0; kt < 2; kt++)
                ah[mt][kt] = *(const short8*)&myE[(nfr + 16 * mt) * 72 + quad * 8 + kt * 32];
        // --- sigma: acc2 = b2[0] + h @ w2s   (consumed before C GEMM) ---
        {
            f32x4 acc2[2];
            acc2[0] = (f32x4){bb2, bb2, bb2, bb2};
            acc2[1] = (f32x4){bb2, bb2, bb2, bb2};
            short8 w2sf[2];
            #pragma unroll
            for (int kt = 0; kt < 2; kt++)
                w2sf[kt] = *(const short8*)&sW2s[nfr * 72 + quad * 8 + kt * 32];
            #pragma unroll
            for (int mt = 0; mt < 2; mt++)
                #pragma unroll
                for (int kt = 0; kt < 2; kt++)
                    acc2[mt] = __builtin_amdgcn_mfma_f32_16x16x32_bf16(
                        ah[mt][kt], w2sf[kt], acc2[mt], 0, 0, 0);
            if (nfr == 0) {
                #pragma unroll
                for (int mt = 0; mt < 2; mt++)
                    #pragma unroll
                    for (int r = 0; r < 4; r++) {
                        const int m = 4 * quad + r + 16 * mt;
                        const float sg = fmaxf(acc2[mt][r], 0.0f);
                        sOm[wave * 128 + qq * 32 + m] = __expf(-sg * dtv);
                    }
            }
        }
        // --- g = relu(h @ C + gv), nt-split to cap live AGPRs at 16 ---
        #pragma unroll
        for (int nth = 0; nth < 2; nth++) {
            f32x4 acc3[2][2];
            #pragma unroll
            for (int mt = 0; mt < 2; mt++)
                #pragma unroll
                for (int j = 0; j < 2; j++) {
                    const float gvi = gv[2 * nth + j];
                    acc3[mt][j] = (f32x4){gvi, gvi, gvi, gvi};
                }
            #pragma unroll
            for (int j = 0; j < 2; j++)
                #pragma unroll
                for (int kt = 0; kt < 2; kt++) {
                    const short8 cf = *(const short8*)
                        &sCt[(4 * nfr + 2 * nth + j) * 72 + quad * 8 + kt * 32];
                    #pragma unroll
                    for (int mt = 0; mt < 2; mt++)
                        acc3[mt][j] = __builtin_amdgcn_mfma_f32_16x16x32_bf16(
                            ah[mt][kt], cf, acc3[mt][j], 0, 0, 0);
                }
            #pragma unroll
            for (int mt = 0; mt < 2; mt++)
                #pragma unroll
                for (int r = 0; r < 4; r++) {
                    const int m = 4 * quad + r + 16 * mt;
                    *(unsigned*)&myE[m * 72 + 4 * nfr + 2 * nth] =
                        pk2bf(fmaxf(acc3[mt][0][r], 0.0f),
                              fmaxf(acc3[mt][1][r], 0.0f));
                }
        }
        // --- V2: rgb = sigmoid(g @ V2 + c2)  (c2 folded into acc init) ---
        {
            f32x4 acc4[2];
            acc4[0] = (f32x4){bc2, bc2, bc2, bc2};
            acc4[1] = (f32x4){bc2, bc2, bc2, bc2};
            short8 agg[2][2];
            #pragma unroll
            for (int mt = 0; mt < 2; mt++)
                #pragma unroll
                for (int kt = 0; kt < 2; kt++)
                    agg[mt][kt] = *(const short8*)&myE[(nfr + 16 * mt) * 72 + quad * 8 + kt * 32];
            short8 v2f[2];
            #pragma unroll
            for (int kt = 0; kt < 2; kt++)
                v2f[kt] = *(const short8*)&sV2t[nfr * 72 + quad * 8 + kt * 32];
            #pragma unroll
            for (int mt = 0; mt < 2; mt++)
                #pragma unroll
                for (int kt = 0; kt < 2; kt++)
                    acc4[mt] = __builtin_amdgcn_mfma_f32_16x16x32_bf16(
                        agg[mt][kt], v2f[kt], acc4[mt], 0, 0, 0);
            if (nfr < 3) {
                #pragma unroll
                for (int mt = 0; mt < 2; mt++)
                    #pragma unroll
                    for (int r = 0; r < 4; r++) {
                        const int m = 4 * quad + r + 16 * mt;
                        const float val = acc4[mt][r];
                        stbf(&sRgb[wave * 384 + (qq * 32 + m) * 3 + nfr],
                             1.0f / (1.0f + __expf(-val)));
                    }
            }
        }
    }

    // ---- exclusive multiplicative scan + weighted reduce (per wave) ----
    const float om0 = sOm[wave * 128 + 2 * lane];
    const float om1 = sOm[wave * 128 + 2 * lane + 1];
    const float al0 = 1.0f - om0;
    const float al1 = 1.0f - om1;

    float inc = om0 * om1;
    #pragma unroll
    for (int off = 1; off < 64; off <<= 1) {
        const float q = __shfl_up(inc, off, 64);
        if (lane >= off) inc *= q;
    }
    float Texc = __shfl_up(inc, 1, 64);
    if (lane == 0) Texc = 1.0f;

    const float T0 = Texc;
    const float T1 = Texc * om0;
    const float a0 = (T0 > 1e-4f) ? 1.0f : 0.0f;
    const float a1 = (T1 > 1e-4f) ? 1.0f : 0.0f;
    const float w0 = T0 * al0 * a0;
    const float w1 = T1 * al1 * a1;

    float cr = w0 * bf2f(sRgb[wave * 384 + (2 * lane) * 3 + 0]) +
               w1 * bf2f(sRgb[wave * 384 + (2 * lane + 1) * 3 + 0]);
    float cg = w0 * bf2f(sRgb[wave * 384 + (2 * lane) * 3 + 1]) +
               w1 * bf2f(sRgb[wave * 384 + (2 * lane + 1) * 3 + 1]);
    float cb = w0 * bf2f(sRgb[wave * 384 + (2 * lane) * 3 + 2]) +
               w1 * bf2f(sRgb[wave * 384 + (2 * lane + 1) * 3 + 2]);
    float tp = (a0 > 0.0f ? om0 : 1.0f) * (a1 > 0.0f ? om1 : 1.0f);

    #pragma unroll
    for (int off = 32; off > 0; off >>= 1) {
        cr += __shfl_xor(cr, off, 64);
        cg += __shfl_xor(cg, off, 64);
        cb += __shfl_xor(cb, off, 64);
        tp *= __shfl_xor(tp, off, 64);
    }

    if (lane == 0) {
        out[ray * 3 + 0] = cr;
        out[ray * 3 + 1] = cg;
        out[ray * 3 + 2] = cb;
        out[NRAYS * 3 + ray] = tp;
    }
}

extern "C" void kernel_launch(void* const* d_in, const int* in_sizes, int n_in,
                              void* d_out, int out_size, void* d_ws, size_t ws_size,
                              hipStream_t stream) {
    const float* orig = (const float*)d_in[0];
    const float* dirs = (const float*)d_in[1];
    const float* tmin = (const float*)d_in[2];
    const float* tmax = (const float*)d_in[3];
    const float* W1   = (const float*)d_in[4];
    const float* b1   = (const float*)d_in[5];
    const float* W2   = (const float*)d_in[6];
    const float* b2   = (const float*)d_in[7];
    const float* V1   = (const float*)d_in[8];
    const float* c1   = (const float*)d_in[9];
    const float* V2   = (const float*)d_in[10];
    const float* c2   = (const float*)d_in[11];

    short* img = (short*)d_ws;
    float* gvc = (float*)((char*)d_ws + GVC_OFF);

    prep_kernel<<<32, 256, 0, stream>>>(W1, b1, W2, b2, V1, c1, V2, img, gvc);
    march_kernel<<<NRAYS / 4, 256, 0, stream>>>(orig, dirs, tmin, tmax,
                                                b2, c2, V1, img, gvc,
                                                (float*)d_out);
}